// Round 3
// baseline (295.868 us; speedup 1.0000x reference)
//
#include <hip/hip_runtime.h>
#include <hip/hip_bf16.h>
#include <cstdint>

#define DEVI static __device__ __forceinline__

typedef __bf16 bf16x8 __attribute__((ext_vector_type(8)));
typedef float f32x4 __attribute__((ext_vector_type(4)));
typedef unsigned short u16x8 __attribute__((ext_vector_type(8)));

constexpr int Bb = 2, Ll = 4096, Dd = 512, Hh = 8;
constexpr int Mm = Bb * Ll;                      // 8192 rows
constexpr float SCALE2 = 1.4426950408889634f / 22.627416997969522f; // log2(e)/sqrt(512)

// LDS row pitch for 64-wide bf16 tiles: 72 shorts = 144 bytes.
// 144 % 16 == 0 keeps ds_*_b128 alignment; 144/4 = 36 banks/row -> 2-way
// read aliasing only (free per m136), vs 16-way at 128B pitch.
constexpr int PITCH = 72;
constexpr int PITCHB = 144;

DEVI unsigned short f2b(float x) {
  __hip_bfloat16 h = __float2bfloat16(x);
  return *reinterpret_cast<unsigned short*>(&h);
}

// ---------------- fp32 -> bf16 convert (8 elems/thread) ----------------
__global__ void __launch_bounds__(256) cvt_kernel(const float* __restrict__ s,
                                                  unsigned short* __restrict__ d, int n8) {
  int i = blockIdx.x * 256 + threadIdx.x;
  if (i >= n8) return;
  const float4* sp = reinterpret_cast<const float4*>(s) + (size_t)i * 2;
  float4 a = sp[0], b2 = sp[1];
  u16x8 o;
  o[0] = f2b(a.x);  o[1] = f2b(a.y);  o[2] = f2b(a.z);  o[3] = f2b(a.w);
  o[4] = f2b(b2.x); o[5] = f2b(b2.y); o[6] = f2b(b2.z); o[7] = f2b(b2.w);
  *reinterpret_cast<u16x8*>(d + (size_t)i * 8) = o;
}

// ---------------- GEMM: C[M][512] = A[M][512] @ W[512][512]^T ----------------
// 128x128 tile, BK=64, 4 waves (2x2). Register-staged, linear padded LDS.
__global__ void __launch_bounds__(256, 2) gemm_bt(const unsigned short* __restrict__ Ab,
                                                  const unsigned short* __restrict__ Wb,
                                                  unsigned short* __restrict__ Cb) {
  __shared__ __align__(16) unsigned short As[128 * PITCH];
  __shared__ __align__(16) unsigned short Bs[128 * PITCH];
  const int t = threadIdx.x, lane = t & 63;
  const int w = t >> 6, wm = w >> 1, wn = w & 1;
  const int c = lane & 15, g = lane >> 4;
  const int z = blockIdx.y;
  const unsigned short* A = Ab + (size_t)z * (Mm * Dd);
  const unsigned short* W = Wb + (size_t)z * (Dd * Dd);
  const int tm = (blockIdx.x >> 2) * 128;
  const int tn = (blockIdx.x & 3) * 128;
  const int r0 = t >> 3, c8 = t & 7;   // staging: rows r0+32u, 16B chunk c8

  f32x4 acc[4][4] = {};
  for (int k0 = 0; k0 < Dd; k0 += 64) {
    u16x8 av[4], bv2[4];
#pragma unroll
    for (int u = 0; u < 4; ++u) {
      int r = u * 32 + r0;
      av[u]  = *reinterpret_cast<const u16x8*>(A + (size_t)(tm + r) * Dd + k0 + c8 * 8);
      bv2[u] = *reinterpret_cast<const u16x8*>(W + (size_t)(tn + r) * Dd + k0 + c8 * 8);
    }
#pragma unroll
    for (int u = 0; u < 4; ++u) {
      int r = u * 32 + r0;
      *reinterpret_cast<u16x8*>((char*)As + r * PITCHB + c8 * 16) = av[u];
      *reinterpret_cast<u16x8*>((char*)Bs + r * PITCHB + c8 * 16) = bv2[u];
    }
    __syncthreads();
#pragma unroll
    for (int kk = 0; kk < 2; ++kk) {
      bf16x8 af[4], bfv[4];
#pragma unroll
      for (int mi = 0; mi < 4; ++mi) {
        int row = wm * 64 + mi * 16 + c;
        af[mi] = *reinterpret_cast<const bf16x8*>(
            (const char*)As + row * PITCHB + kk * 64 + g * 16);
      }
#pragma unroll
      for (int ni = 0; ni < 4; ++ni) {
        int row = wn * 64 + ni * 16 + c;
        bfv[ni] = *reinterpret_cast<const bf16x8*>(
            (const char*)Bs + row * PITCHB + kk * 64 + g * 16);
      }
#pragma unroll
      for (int mi = 0; mi < 4; ++mi)
#pragma unroll
        for (int ni = 0; ni < 4; ++ni)
          acc[mi][ni] = __builtin_amdgcn_mfma_f32_16x16x32_bf16(af[mi], bfv[ni], acc[mi][ni], 0, 0, 0);
    }
    __syncthreads();
  }
  // epilogue: C layout col=lane&15, row=(lane>>4)*4+reg
  unsigned short* C = Cb + (size_t)z * (Mm * Dd);
#pragma unroll
  for (int mi = 0; mi < 4; ++mi)
#pragma unroll
    for (int j = 0; j < 4; ++j) {
      size_t row = (size_t)(tm + wm * 64 + mi * 16 + g * 4 + j);
      size_t base = row * Dd + tn + wn * 64 + c;
#pragma unroll
      for (int ni = 0; ni < 4; ++ni) C[base + ni * 16] = f2b(acc[mi][ni][j]);
    }
}

// ---------------- V [m][512] -> Vt [b][h][dh=64][L] ----------------
__global__ void __launch_bounds__(256) transpose_v(const unsigned short* __restrict__ V,
                                                   unsigned short* __restrict__ Vt) {
  __shared__ unsigned short s[64][PITCH];
  const int t = threadIdx.x;
  const int bh = blockIdx.y, b = bh >> 3, h = bh & 7;
  const int l0 = blockIdx.x * 64;
  const int r0 = t >> 3, c8 = t & 7;
#pragma unroll
  for (int u = 0; u < 2; ++u) {
    int r = u * 32 + r0;   // l-index in tile
    u16x8 v = *reinterpret_cast<const u16x8*>(
        V + (size_t)(b * Ll + l0 + r) * Dd + h * 64 + c8 * 8);
#pragma unroll
    for (int e = 0; e < 8; ++e) s[r][c8 * 8 + e] = v[e];
  }
  __syncthreads();
#pragma unroll
  for (int u = 0; u < 2; ++u) {
    int dh = u * 32 + r0;        // 0..63
    int lp = c8 * 8;
    u16x8 o;
#pragma unroll
    for (int e = 0; e < 8; ++e) o[e] = s[lp + e][dh];
    *reinterpret_cast<u16x8*>(Vt + (size_t)(bh * 64 + dh) * Ll + l0 + lp) = o;
  }
}

// ---------------- causal flash attention (writes fp32 directly to d_out) ----
// grid (L/64, B*H), 4 waves; wave w owns q-rows q0+16w..+15. 64-key tiles.
__global__ void __launch_bounds__(256, 2) attn_kernel(const unsigned short* __restrict__ Q,
                                                      const unsigned short* __restrict__ K,
                                                      const unsigned short* __restrict__ Vt,
                                                      float* __restrict__ O) {
  __shared__ __align__(16) unsigned short Ks[64 * PITCH];
  __shared__ __align__(16) unsigned short Vs[64 * PITCH];   // V^T tile: [dh][key]
  __shared__ __align__(16) unsigned short Ps[4][16 * PITCH];
  const int t = threadIdx.x, lane = t & 63, w = t >> 6;
  const int c = lane & 15, g = lane >> 4;
  const int q0 = blockIdx.x * 64;
  const int bh = blockIdx.y, b = bh >> 3, h = bh & 7;
  const int r0 = t >> 3, c8 = t & 7;

  const unsigned short* Qrow = Q + (size_t)(b * Ll + q0 + w * 16 + c) * Dd + h * 64;
  bf16x8 aq0 = *reinterpret_cast<const bf16x8*>(Qrow + g * 8);
  bf16x8 aq1 = *reinterpret_cast<const bf16x8*>(Qrow + 32 + g * 8);

  float m_r[4], s_r[4];
  f32x4 oacc[4] = {};
#pragma unroll
  for (int j = 0; j < 4; ++j) { m_r[j] = -3e38f; s_r[j] = 0.f; }

  const size_t kbase = (size_t)(b * Ll) * Dd + h * 64;
  const size_t vbase = (size_t)(bh * 64) * Ll;
  const int ntiles = q0 / 64 + 1;
  for (int kt = 0; kt < ntiles; ++kt) {
    u16x8 kv[2], vv[2];
#pragma unroll
    for (int u = 0; u < 2; ++u) {
      int r = u * 32 + r0;
      kv[u] = *reinterpret_cast<const u16x8*>(K + kbase + (size_t)(kt * 64 + r) * Dd + c8 * 8);
      vv[u] = *reinterpret_cast<const u16x8*>(Vt + vbase + (size_t)r * Ll + kt * 64 + c8 * 8);
    }
#pragma unroll
    for (int u = 0; u < 2; ++u) {
      int r = u * 32 + r0;
      *reinterpret_cast<u16x8*>((char*)Ks + r * PITCHB + c8 * 16) = kv[u];
      *reinterpret_cast<u16x8*>((char*)Vs + r * PITCHB + c8 * 16) = vv[u];
    }
    __syncthreads();
    // QK^T: S (16 q x 64 key) per wave
    f32x4 sacc[4] = {};
#pragma unroll
    for (int kk = 0; kk < 2; ++kk) {
      bf16x8 aq = kk ? aq1 : aq0;
#pragma unroll
      for (int ni = 0; ni < 4; ++ni) {
        int row = ni * 16 + c;   // key row
        bf16x8 bk = *reinterpret_cast<const bf16x8*>(
            (const char*)Ks + row * PITCHB + kk * 64 + g * 16);
        sacc[ni] = __builtin_amdgcn_mfma_f32_16x16x32_bf16(aq, bk, sacc[ni], 0, 0, 0);
      }
    }
    // online softmax (exp2 domain)
    float p[4][4];
    float pm[4] = {-3e38f, -3e38f, -3e38f, -3e38f};
#pragma unroll
    for (int ni = 0; ni < 4; ++ni)
#pragma unroll
      for (int j = 0; j < 4; ++j) {
        int kpos = kt * 64 + ni * 16 + c;
        int qpos = q0 + w * 16 + g * 4 + j;
        float v = (kpos > qpos) ? -3e38f : sacc[ni][j] * SCALE2;
        p[ni][j] = v;
        pm[j] = fmaxf(pm[j], v);
      }
#pragma unroll
    for (int d = 1; d < 16; d <<= 1)
#pragma unroll
      for (int j = 0; j < 4; ++j) pm[j] = fmaxf(pm[j], __shfl_xor(pm[j], d));
    float alpha[4], rs[4];
#pragma unroll
    for (int j = 0; j < 4; ++j) {
      float mn = fmaxf(m_r[j], pm[j]);
      alpha[j] = exp2f(m_r[j] - mn);
      m_r[j] = mn;
      rs[j] = 0.f;
    }
#pragma unroll
    for (int ni = 0; ni < 4; ++ni)
#pragma unroll
      for (int j = 0; j < 4; ++j) {
        float e = exp2f(p[ni][j] - m_r[j]);
        p[ni][j] = e;
        rs[j] += e;
      }
#pragma unroll
    for (int d = 1; d < 16; d <<= 1)
#pragma unroll
      for (int j = 0; j < 4; ++j) rs[j] += __shfl_xor(rs[j], d);
#pragma unroll
    for (int j = 0; j < 4; ++j) s_r[j] = s_r[j] * alpha[j] + rs[j];
#pragma unroll
    for (int ni = 0; ni < 4; ++ni)
#pragma unroll
      for (int j = 0; j < 4; ++j) oacc[ni][j] *= alpha[j];
    // P -> per-wave LDS (bf16, linear padded) for PV A-fragment relayout
    unsigned short* Pw = (unsigned short*)Ps[w];
#pragma unroll
    for (int ni = 0; ni < 4; ++ni)
#pragma unroll
      for (int j = 0; j < 4; ++j) {
        int q = g * 4 + j;
        *(unsigned short*)((char*)Pw + q * PITCHB + (ni * 16 + c) * 2) = f2b(p[ni][j]);
      }
    __syncthreads();
    // PV: O += P @ V
    bf16x8 pa[2];
#pragma unroll
    for (int kk = 0; kk < 2; ++kk)
      pa[kk] = *reinterpret_cast<const bf16x8*>(
          (const char*)Pw + c * PITCHB + kk * 64 + g * 16);
#pragma unroll
    for (int ni = 0; ni < 4; ++ni) {
      int row = ni * 16 + c;   // dh row of V^T
#pragma unroll
      for (int kk = 0; kk < 2; ++kk) {
        bf16x8 bv = *reinterpret_cast<const bf16x8*>(
            (const char*)Vs + row * PITCHB + kk * 64 + g * 16);
        oacc[ni] = __builtin_amdgcn_mfma_f32_16x16x32_bf16(pa[kk], bv, oacc[ni], 0, 0, 0);
      }
    }
    __syncthreads();
  }
  // epilogue: out[b,l,h*64+dh] fp32 directly to d_out (reference has NO Wo projection)
#pragma unroll
  for (int j = 0; j < 4; ++j) {
    float inv = 1.0f / s_r[j];
    size_t row = (size_t)(b * Ll + q0 + w * 16 + g * 4 + j);
    float* Orow = O + row * Dd + h * 64 + c;
#pragma unroll
    for (int ni = 0; ni < 4; ++ni) Orow[ni * 16] = oacc[ni][j] * inv;
  }
}

// ---------------- launcher ----------------
extern "C" void kernel_launch(void* const* d_in, const int* in_sizes, int n_in,
                              void* d_out, int out_size, void* d_ws, size_t ws_size,
                              hipStream_t stream) {
  const float* query = (const float*)d_in[0];
  const float* key   = (const float*)d_in[1];
  const float* value = (const float*)d_in[2];
  // d_in[3] = causal mask (implied by kernel; unused)
  const float* Wq = (const float*)d_in[4];
  const float* Wk = (const float*)d_in[5];
  const float* Wv = (const float*)d_in[6];
  // d_in[7] = Wo -- present in inputs but NOT used by the reference

  unsigned short* Xbf  = (unsigned short*)d_ws;                 // 3 x M x D
  unsigned short* Wbf  = Xbf + (size_t)3 * Mm * Dd;             // 3 x D x D
  unsigned short* QKV  = Wbf + (size_t)3 * Dd * Dd;             // 3 x M x D
  unsigned short* Vt   = QKV + (size_t)3 * Mm * Dd;             // B*H*64 x L

  const int nbig = Mm * Dd / 8, nsmall = Dd * Dd / 8;
  cvt_kernel<<<nbig / 256, 256, 0, stream>>>(query, Xbf, nbig);
  cvt_kernel<<<nbig / 256, 256, 0, stream>>>(key,   Xbf + (size_t)Mm * Dd, nbig);
  cvt_kernel<<<nbig / 256, 256, 0, stream>>>(value, Xbf + (size_t)2 * Mm * Dd, nbig);
  cvt_kernel<<<nsmall / 256, 256, 0, stream>>>(Wq, Wbf, nsmall);
  cvt_kernel<<<nsmall / 256, 256, 0, stream>>>(Wk, Wbf + (size_t)Dd * Dd, nsmall);
  cvt_kernel<<<nsmall / 256, 256, 0, stream>>>(Wv, Wbf + (size_t)2 * Dd * Dd, nsmall);

  gemm_bt<<<dim3(256, 3), 256, 0, stream>>>(Xbf, Wbf, QKV);

  unsigned short* Qb = QKV;
  unsigned short* Kb = QKV + (size_t)Mm * Dd;
  unsigned short* Vb = QKV + (size_t)2 * Mm * Dd;
  transpose_v<<<dim3(64, 16), 256, 0, stream>>>(Vb, Vt);
  attn_kernel<<<dim3(64, 16), 256, 0, stream>>>(Qb, Kb, Vt, (float*)d_out);
}

// Round 4
// 190.073 us; speedup vs baseline: 1.5566x; 1.5566x over previous
//
#include <hip/hip_runtime.h>
#include <hip/hip_bf16.h>
#include <cstdint>

#define DEVI static __device__ __forceinline__

typedef __bf16 bf16x8 __attribute__((ext_vector_type(8)));
typedef float f32x4 __attribute__((ext_vector_type(4)));
typedef unsigned short u16x8 __attribute__((ext_vector_type(8)));

constexpr int Bb = 2, Ll = 4096, Dd = 512, Hh = 8;
constexpr int Mm = Bb * Ll;                      // 8192 rows
constexpr float SCALE2 = 1.4426950408889634f / 22.627416997969522f; // log2(e)/sqrt(512)

// LDS row pitch for 64-wide bf16 tiles: 72 shorts = 144 bytes.
// 144 % 16 == 0 keeps ds_*_b128 alignment; 144/4 = 36 banks/row -> 2-way
// read aliasing only (free per m136), vs 16-way at 128B pitch.
constexpr int PITCH = 72;
constexpr int PITCHB = 144;

DEVI unsigned short f2b(float x) {
  __hip_bfloat16 h = __float2bfloat16(x);
  return *reinterpret_cast<unsigned short*>(&h);
}

// ---------------- fp32 -> bf16 convert (8 elems/thread) ----------------
__global__ void __launch_bounds__(256) cvt_kernel(const float* __restrict__ s,
                                                  unsigned short* __restrict__ d, int n8) {
  int i = blockIdx.x * 256 + threadIdx.x;
  if (i >= n8) return;
  const float4* sp = reinterpret_cast<const float4*>(s) + (size_t)i * 2;
  float4 a = sp[0], b2 = sp[1];
  u16x8 o;
  o[0] = f2b(a.x);  o[1] = f2b(a.y);  o[2] = f2b(a.z);  o[3] = f2b(a.w);
  o[4] = f2b(b2.x); o[5] = f2b(b2.y); o[6] = f2b(b2.z); o[7] = f2b(b2.w);
  *reinterpret_cast<u16x8*>(d + (size_t)i * 8) = o;
}

// ---------------- GEMM: C[M][512] = A[M][512] @ W[512][512]^T ----------------
// 128x128 tile, BK=64, 4 waves (2x2). Register-staged, linear padded LDS.
__global__ void __launch_bounds__(256, 2) gemm_bt(const unsigned short* __restrict__ Ab,
                                                  const unsigned short* __restrict__ Wb,
                                                  unsigned short* __restrict__ Cb) {
  __shared__ __align__(16) unsigned short As[128 * PITCH];
  __shared__ __align__(16) unsigned short Bs[128 * PITCH];
  const int t = threadIdx.x, lane = t & 63;
  const int w = t >> 6, wm = w >> 1, wn = w & 1;
  const int c = lane & 15, g = lane >> 4;
  const int z = blockIdx.y;
  const unsigned short* A = Ab + (size_t)z * (Mm * Dd);
  const unsigned short* W = Wb + (size_t)z * (Dd * Dd);
  const int tm = (blockIdx.x >> 2) * 128;
  const int tn = (blockIdx.x & 3) * 128;
  const int r0 = t >> 3, c8 = t & 7;   // staging: rows r0+32u, 16B chunk c8

  f32x4 acc[4][4] = {};
  for (int k0 = 0; k0 < Dd; k0 += 64) {
    u16x8 av[4], bv2[4];
#pragma unroll
    for (int u = 0; u < 4; ++u) {
      int r = u * 32 + r0;
      av[u]  = *reinterpret_cast<const u16x8*>(A + (size_t)(tm + r) * Dd + k0 + c8 * 8);
      bv2[u] = *reinterpret_cast<const u16x8*>(W + (size_t)(tn + r) * Dd + k0 + c8 * 8);
    }
#pragma unroll
    for (int u = 0; u < 4; ++u) {
      int r = u * 32 + r0;
      *reinterpret_cast<u16x8*>((char*)As + r * PITCHB + c8 * 16) = av[u];
      *reinterpret_cast<u16x8*>((char*)Bs + r * PITCHB + c8 * 16) = bv2[u];
    }
    __syncthreads();
#pragma unroll
    for (int kk = 0; kk < 2; ++kk) {
      bf16x8 af[4], bfv[4];
#pragma unroll
      for (int mi = 0; mi < 4; ++mi) {
        int row = wm * 64 + mi * 16 + c;
        af[mi] = *reinterpret_cast<const bf16x8*>(
            (const char*)As + row * PITCHB + kk * 64 + g * 16);
      }
#pragma unroll
      for (int ni = 0; ni < 4; ++ni) {
        int row = wn * 64 + ni * 16 + c;
        bfv[ni] = *reinterpret_cast<const bf16x8*>(
            (const char*)Bs + row * PITCHB + kk * 64 + g * 16);
      }
#pragma unroll
      for (int mi = 0; mi < 4; ++mi)
#pragma unroll
        for (int ni = 0; ni < 4; ++ni)
          acc[mi][ni] = __builtin_amdgcn_mfma_f32_16x16x32_bf16(af[mi], bfv[ni], acc[mi][ni], 0, 0, 0);
    }
    __syncthreads();
  }
  // epilogue: C layout col=lane&15, row=(lane>>4)*4+reg
  unsigned short* C = Cb + (size_t)z * (Mm * Dd);
#pragma unroll
  for (int mi = 0; mi < 4; ++mi)
#pragma unroll
    for (int j = 0; j < 4; ++j) {
      size_t row = (size_t)(tm + wm * 64 + mi * 16 + g * 4 + j);
      size_t base = row * Dd + tn + wn * 64 + c;
#pragma unroll
      for (int ni = 0; ni < 4; ++ni) C[base + ni * 16] = f2b(acc[mi][ni][j]);
    }
}

// ---------------- V [m][512] -> Vt [b][h][dh=64][L] ----------------
__global__ void __launch_bounds__(256) transpose_v(const unsigned short* __restrict__ V,
                                                   unsigned short* __restrict__ Vt) {
  __shared__ unsigned short s[64][PITCH];
  const int t = threadIdx.x;
  const int bh = blockIdx.y, b = bh >> 3, h = bh & 7;
  const int l0 = blockIdx.x * 64;
  const int r0 = t >> 3, c8 = t & 7;
#pragma unroll
  for (int u = 0; u < 2; ++u) {
    int r = u * 32 + r0;   // l-index in tile
    u16x8 v = *reinterpret_cast<const u16x8*>(
        V + (size_t)(b * Ll + l0 + r) * Dd + h * 64 + c8 * 8);
#pragma unroll
    for (int e = 0; e < 8; ++e) s[r][c8 * 8 + e] = v[e];
  }
  __syncthreads();
#pragma unroll
  for (int u = 0; u < 2; ++u) {
    int dh = u * 32 + r0;        // 0..63
    int lp = c8 * 8;
    u16x8 o;
#pragma unroll
    for (int e = 0; e < 8; ++e) o[e] = s[lp + e][dh];
    *reinterpret_cast<u16x8*>(Vt + (size_t)(bh * 64 + dh) * Ll + l0 + lp) = o;
  }
}

// ---------------- causal flash attention (writes fp32 directly to d_out) ----
// 512 threads = 8 waves; QBLK=128 (wave w owns q-rows q0+16w..+15).
// K/V double-buffered in LDS; one barrier per 64-key tile; T14 async staging.
// Block remap: XCD x=b&7 owns bh {2x,2x+1} (K/V L2-resident per XCD);
// CU-paired blocks (b, b+256) get qi and 31-qi for load balance.
__global__ void __launch_bounds__(512, 4) attn_kernel(const unsigned short* __restrict__ Q,
                                                      const unsigned short* __restrict__ K,
                                                      const unsigned short* __restrict__ Vt,
                                                      float* __restrict__ O) {
  __shared__ __align__(16) unsigned short Ks[2][64 * PITCH];
  __shared__ __align__(16) unsigned short Vs[2][64 * PITCH];   // V^T tile: [dh][key]
  __shared__ __align__(16) unsigned short Ps[8][16 * PITCH];
  const int t = threadIdx.x, lane = t & 63, w = t >> 6;
  const int c = lane & 15, g = lane >> 4;
  // block remap
  const int bidx = blockIdx.x;
  const int xg = bidx & 7, rr = bidx >> 3, hi = rr >> 5;
  const int bh = 2 * xg + hi;
  int qi = rr & 31; if (hi) qi = 31 - qi;
  const int q0 = qi * 128;
  const int b = bh >> 3, h = bh & 7;
  const int r0 = t >> 3, c8 = t & 7;    // staging: row r0 (0..63), 16B chunk c8

  const unsigned short* Qrow = Q + (size_t)(b * Ll + q0 + w * 16 + c) * Dd + h * 64;
  bf16x8 aq0 = *reinterpret_cast<const bf16x8*>(Qrow + g * 8);
  bf16x8 aq1 = *reinterpret_cast<const bf16x8*>(Qrow + 32 + g * 8);

  float m_r[4], s_r[4];
  f32x4 oacc[4] = {};
#pragma unroll
  for (int j = 0; j < 4; ++j) { m_r[j] = -3e38f; s_r[j] = 0.f; }

  const size_t kbase = (size_t)(b * Ll) * Dd + h * 64;
  const size_t vbase = (size_t)(bh * 64) * Ll;
  const int ntiles = 2 * qi + 2;
  const int ktmax = (q0 + w * 16 + 15) >> 6;        // last tile this wave needs
  const int qmin = q0 + w * 16;                     // min q-row of this wave

  // prologue: stage tile 0 into buffer 0
  u16x8 kv = *reinterpret_cast<const u16x8*>(K + kbase + (size_t)r0 * Dd + c8 * 8);
  u16x8 vv = *reinterpret_cast<const u16x8*>(Vt + vbase + (size_t)r0 * Ll + c8 * 8);
  *reinterpret_cast<u16x8*>((char*)Ks[0] + r0 * PITCHB + c8 * 16) = kv;
  *reinterpret_cast<u16x8*>((char*)Vs[0] + r0 * PITCHB + c8 * 16) = vv;

  for (int kt = 0; kt < ntiles; ++kt) {
    const int cur = kt & 1;
    __syncthreads();                 // buf[cur] staged; prev-tile reads done
    const bool pf = (kt + 1 < ntiles);
    if (pf) {                        // issue next tile's loads (latency hides under compute)
      kv = *reinterpret_cast<const u16x8*>(K + kbase + (size_t)((kt + 1) * 64 + r0) * Dd + c8 * 8);
      vv = *reinterpret_cast<const u16x8*>(Vt + vbase + (size_t)r0 * Ll + (kt + 1) * 64 + c8 * 8);
    }
    if (kt <= ktmax) {               // wave-uniform causal skip
      // QK^T: S (16 q x 64 key)
      f32x4 sacc[4] = {};
      __builtin_amdgcn_s_setprio(1);
#pragma unroll
      for (int kk = 0; kk < 2; ++kk) {
        bf16x8 aq = kk ? aq1 : aq0;
#pragma unroll
        for (int ni = 0; ni < 4; ++ni) {
          int row = ni * 16 + c;   // key row
          bf16x8 bk = *reinterpret_cast<const bf16x8*>(
              (const char*)Ks[cur] + row * PITCHB + kk * 64 + g * 16);
          sacc[ni] = __builtin_amdgcn_mfma_f32_16x16x32_bf16(aq, bk, sacc[ni], 0, 0, 0);
        }
      }
      __builtin_amdgcn_s_setprio(0);
      // online softmax (exp2 domain)
      float p[4][4];
      float pm[4] = {-3e38f, -3e38f, -3e38f, -3e38f};
      const bool needMask = (kt * 64 + 63 > qmin);
      if (needMask) {
#pragma unroll
        for (int ni = 0; ni < 4; ++ni)
#pragma unroll
          for (int j = 0; j < 4; ++j) {
            int kpos = kt * 64 + ni * 16 + c;
            int qpos = qmin + g * 4 + j;
            float v = (kpos > qpos) ? -3e38f : sacc[ni][j] * SCALE2;
            p[ni][j] = v;
            pm[j] = fmaxf(pm[j], v);
          }
      } else {
#pragma unroll
        for (int ni = 0; ni < 4; ++ni)
#pragma unroll
          for (int j = 0; j < 4; ++j) {
            float v = sacc[ni][j] * SCALE2;
            p[ni][j] = v;
            pm[j] = fmaxf(pm[j], v);
          }
      }
#pragma unroll
      for (int d = 1; d < 16; d <<= 1)
#pragma unroll
        for (int j = 0; j < 4; ++j) pm[j] = fmaxf(pm[j], __shfl_xor(pm[j], d));
      float alpha[4], rs[4];
#pragma unroll
      for (int j = 0; j < 4; ++j) {
        float mn = fmaxf(m_r[j], pm[j]);
        alpha[j] = exp2f(m_r[j] - mn);
        m_r[j] = mn;
        rs[j] = 0.f;
      }
#pragma unroll
      for (int ni = 0; ni < 4; ++ni)
#pragma unroll
        for (int j = 0; j < 4; ++j) {
          float e = exp2f(p[ni][j] - m_r[j]);
          p[ni][j] = e;
          rs[j] += e;
        }
#pragma unroll
      for (int d = 1; d < 16; d <<= 1)
#pragma unroll
        for (int j = 0; j < 4; ++j) rs[j] += __shfl_xor(rs[j], d);
#pragma unroll
      for (int j = 0; j < 4; ++j) s_r[j] = s_r[j] * alpha[j] + rs[j];
#pragma unroll
      for (int ni = 0; ni < 4; ++ni)
#pragma unroll
        for (int j = 0; j < 4; ++j) oacc[ni][j] *= alpha[j];
      // P -> per-wave LDS (wave-private; fence instead of barrier)
      unsigned short* Pw = (unsigned short*)Ps[w];
#pragma unroll
      for (int ni = 0; ni < 4; ++ni)
#pragma unroll
        for (int j = 0; j < 4; ++j) {
          int q = g * 4 + j;
          *(unsigned short*)((char*)Pw + q * PITCHB + (ni * 16 + c) * 2) = f2b(p[ni][j]);
        }
      asm volatile("s_waitcnt lgkmcnt(0)" ::: "memory");
      __builtin_amdgcn_sched_barrier(0);
      // PV: O += P @ V
      bf16x8 pa[2];
#pragma unroll
      for (int kk = 0; kk < 2; ++kk)
        pa[kk] = *reinterpret_cast<const bf16x8*>(
            (const char*)Pw + c * PITCHB + kk * 64 + g * 16);
      __builtin_amdgcn_s_setprio(1);
#pragma unroll
      for (int ni = 0; ni < 4; ++ni) {
        int row = ni * 16 + c;   // dh row of V^T
#pragma unroll
        for (int kk = 0; kk < 2; ++kk) {
          bf16x8 bv = *reinterpret_cast<const bf16x8*>(
              (const char*)Vs[cur] + row * PITCHB + kk * 64 + g * 16);
          oacc[ni] = __builtin_amdgcn_mfma_f32_16x16x32_bf16(pa[kk], bv, oacc[ni], 0, 0, 0);
        }
      }
      __builtin_amdgcn_s_setprio(0);
    }
    if (pf) {                        // write next tile into the other buffer
      *reinterpret_cast<u16x8*>((char*)Ks[cur ^ 1] + r0 * PITCHB + c8 * 16) = kv;
      *reinterpret_cast<u16x8*>((char*)Vs[cur ^ 1] + r0 * PITCHB + c8 * 16) = vv;
    }
  }
  // epilogue: out[b,l,h*64+dh] fp32 directly to d_out (reference has NO Wo projection)
#pragma unroll
  for (int j = 0; j < 4; ++j) {
    float inv = 1.0f / s_r[j];
    size_t row = (size_t)(b * Ll + q0 + w * 16 + g * 4 + j);
    float* Orow = O + row * Dd + h * 64 + c;
#pragma unroll
    for (int ni = 0; ni < 4; ++ni) Orow[ni * 16] = oacc[ni][j] * inv;
  }
}

// ---------------- launcher ----------------
extern "C" void kernel_launch(void* const* d_in, const int* in_sizes, int n_in,
                              void* d_out, int out_size, void* d_ws, size_t ws_size,
                              hipStream_t stream) {
  const float* query = (const float*)d_in[0];
  const float* key   = (const float*)d_in[1];
  const float* value = (const float*)d_in[2];
  // d_in[3] = causal mask (implied by kernel; unused)
  const float* Wq = (const float*)d_in[4];
  const float* Wk = (const float*)d_in[5];
  const float* Wv = (const float*)d_in[6];
  // d_in[7] = Wo -- present in inputs but NOT used by the reference

  unsigned short* Xbf  = (unsigned short*)d_ws;                 // 3 x M x D
  unsigned short* Wbf  = Xbf + (size_t)3 * Mm * Dd;             // 3 x D x D
  unsigned short* QKV  = Wbf + (size_t)3 * Dd * Dd;             // 3 x M x D
  unsigned short* Vt   = QKV + (size_t)3 * Mm * Dd;             // B*H*64 x L

  const int nbig = Mm * Dd / 8, nsmall = Dd * Dd / 8;
  cvt_kernel<<<nbig / 256, 256, 0, stream>>>(query, Xbf, nbig);
  cvt_kernel<<<nbig / 256, 256, 0, stream>>>(key,   Xbf + (size_t)Mm * Dd, nbig);
  cvt_kernel<<<nbig / 256, 256, 0, stream>>>(value, Xbf + (size_t)2 * Mm * Dd, nbig);
  cvt_kernel<<<nsmall / 256, 256, 0, stream>>>(Wq, Wbf, nsmall);
  cvt_kernel<<<nsmall / 256, 256, 0, stream>>>(Wk, Wbf + (size_t)Dd * Dd, nsmall);
  cvt_kernel<<<nsmall / 256, 256, 0, stream>>>(Wv, Wbf + (size_t)2 * Dd * Dd, nsmall);

  gemm_bt<<<dim3(256, 3), 256, 0, stream>>>(Xbf, Wbf, QKV);

  unsigned short* Qb = QKV;
  unsigned short* Kb = QKV + (size_t)Mm * Dd;
  unsigned short* Vb = QKV + (size_t)2 * Mm * Dd;
  transpose_v<<<dim3(64, 16), 256, 0, stream>>>(Vb, Vt);
  attn_kernel<<<512, 512, 0, stream>>>(Qb, Kb, Vt, (float*)d_out);
}

// Round 6
// 157.435 us; speedup vs baseline: 1.8793x; 1.2073x over previous
//
#include <hip/hip_runtime.h>
#include <hip/hip_bf16.h>
#include <cstdint>

#define DEVI static __device__ __forceinline__

typedef __bf16 bf16x8 __attribute__((ext_vector_type(8)));
typedef float f32x4 __attribute__((ext_vector_type(4)));
typedef float f32x16 __attribute__((ext_vector_type(16)));
typedef unsigned short u16x8 __attribute__((ext_vector_type(8)));

constexpr int Bb = 2, Ll = 4096, Dd = 512, Hh = 8;
constexpr int Mm = Bb * Ll;                      // 8192 rows
constexpr float SCALE2 = 1.4426950408889634f / 22.627416997969522f; // log2(e)/sqrt(512)

// GEMM LDS pitch (kept from round 3/4): 72 shorts = 144B
constexpr int PITCH = 72;
constexpr int PITCHB = 144;

DEVI unsigned short f2b(float x) {
  __hip_bfloat16 h = __float2bfloat16(x);
  return *reinterpret_cast<unsigned short*>(&h);
}

// ---------------- fp32 -> bf16 convert (8 elems/thread) ----------------
__global__ void __launch_bounds__(256) cvt_kernel(const float* __restrict__ s,
                                                  unsigned short* __restrict__ d, int n8) {
  int i = blockIdx.x * 256 + threadIdx.x;
  if (i >= n8) return;
  const float4* sp = reinterpret_cast<const float4*>(s) + (size_t)i * 2;
  float4 a = sp[0], b2 = sp[1];
  u16x8 o;
  o[0] = f2b(a.x);  o[1] = f2b(a.y);  o[2] = f2b(a.z);  o[3] = f2b(a.w);
  o[4] = f2b(b2.x); o[5] = f2b(b2.y); o[6] = f2b(b2.z); o[7] = f2b(b2.w);
  *reinterpret_cast<u16x8*>(d + (size_t)i * 8) = o;
}

// ---------------- GEMM: C[M][512] = A[M][512] @ W[512][512]^T ----------------
__global__ void __launch_bounds__(256, 2) gemm_bt(const unsigned short* __restrict__ Ab,
                                                  const unsigned short* __restrict__ Wb,
                                                  unsigned short* __restrict__ Cb) {
  __shared__ __align__(16) unsigned short As[128 * PITCH];
  __shared__ __align__(16) unsigned short Bs[128 * PITCH];
  const int t = threadIdx.x, lane = t & 63;
  const int w = t >> 6, wm = w >> 1, wn = w & 1;
  const int c = lane & 15, g = lane >> 4;
  const int z = blockIdx.y;
  const unsigned short* A = Ab + (size_t)z * (Mm * Dd);
  const unsigned short* W = Wb + (size_t)z * (Dd * Dd);
  const int tm = (blockIdx.x >> 2) * 128;
  const int tn = (blockIdx.x & 3) * 128;
  const int r0 = t >> 3, c8 = t & 7;

  f32x4 acc[4][4] = {};
  for (int k0 = 0; k0 < Dd; k0 += 64) {
    u16x8 av[4], bv2[4];
#pragma unroll
    for (int u = 0; u < 4; ++u) {
      int r = u * 32 + r0;
      av[u]  = *reinterpret_cast<const u16x8*>(A + (size_t)(tm + r) * Dd + k0 + c8 * 8);
      bv2[u] = *reinterpret_cast<const u16x8*>(W + (size_t)(tn + r) * Dd + k0 + c8 * 8);
    }
#pragma unroll
    for (int u = 0; u < 4; ++u) {
      int r = u * 32 + r0;
      *reinterpret_cast<u16x8*>((char*)As + r * PITCHB + c8 * 16) = av[u];
      *reinterpret_cast<u16x8*>((char*)Bs + r * PITCHB + c8 * 16) = bv2[u];
    }
    __syncthreads();
#pragma unroll
    for (int kk = 0; kk < 2; ++kk) {
      bf16x8 af[4], bfv[4];
#pragma unroll
      for (int mi = 0; mi < 4; ++mi) {
        int row = wm * 64 + mi * 16 + c;
        af[mi] = *reinterpret_cast<const bf16x8*>(
            (const char*)As + row * PITCHB + kk * 64 + g * 16);
      }
#pragma unroll
      for (int ni = 0; ni < 4; ++ni) {
        int row = wn * 64 + ni * 16 + c;
        bfv[ni] = *reinterpret_cast<const bf16x8*>(
            (const char*)Bs + row * PITCHB + kk * 64 + g * 16);
      }
#pragma unroll
      for (int mi = 0; mi < 4; ++mi)
#pragma unroll
        for (int ni = 0; ni < 4; ++ni)
          acc[mi][ni] = __builtin_amdgcn_mfma_f32_16x16x32_bf16(af[mi], bfv[ni], acc[mi][ni], 0, 0, 0);
    }
    __syncthreads();
  }
  unsigned short* C = Cb + (size_t)z * (Mm * Dd);
#pragma unroll
  for (int mi = 0; mi < 4; ++mi)
#pragma unroll
    for (int j = 0; j < 4; ++j) {
      size_t row = (size_t)(tm + wm * 64 + mi * 16 + g * 4 + j);
      size_t base = row * Dd + tn + wn * 64 + c;
#pragma unroll
      for (int ni = 0; ni < 4; ++ni) C[base + ni * 16] = f2b(acc[mi][ni][j]);
    }
}

// ---------------- V [m][512] -> Vt [b][h][dh=64][L] ----------------
__global__ void __launch_bounds__(256) transpose_v(const unsigned short* __restrict__ V,
                                                   unsigned short* __restrict__ Vt) {
  __shared__ unsigned short s[64][PITCH];
  const int t = threadIdx.x;
  const int bh = blockIdx.y, b = bh >> 3, h = bh & 7;
  const int l0 = blockIdx.x * 64;
  const int r0 = t >> 3, c8 = t & 7;
#pragma unroll
  for (int u = 0; u < 2; ++u) {
    int r = u * 32 + r0;
    u16x8 v = *reinterpret_cast<const u16x8*>(
        V + (size_t)(b * Ll + l0 + r) * Dd + h * 64 + c8 * 8);
#pragma unroll
    for (int e = 0; e < 8; ++e) s[r][c8 * 8 + e] = v[e];
  }
  __syncthreads();
#pragma unroll
  for (int u = 0; u < 2; ++u) {
    int dh = u * 32 + r0;
    int lp = c8 * 8;
    u16x8 o;
#pragma unroll
    for (int e = 0; e < 8; ++e) o[e] = s[lp + e][dh];
    *reinterpret_cast<u16x8*>(Vt + (size_t)(bh * 64 + dh) * Ll + l0 + lp) = o;
  }
}

// ---------------- causal flash attention, 32x32 swapped-operand structure ----
// 256 threads = 4 waves; wave owns 32 q-rows (QBLK=128). 64-key tiles,
// K/V double-buffered in swizzled LDS (32KB). Softmax fully in-register:
// QK^T = mfma(K,Q) -> lane-pair holds a full q-row; PV = mfma(V^T,P) -> oacc
// cols = own q (lane-local rescale). O^T transposed back via LDS epilogue.
// NOTE: no pointer arrays into LDS (gfx950 rejects the addrspacecast static
// initializer) -- buffer selection is done with byte offsets off one base.
__global__ void __launch_bounds__(256, 2) attn_kernel(const unsigned short* __restrict__ Q,
                                                      const unsigned short* __restrict__ K,
                                                      const unsigned short* __restrict__ Vt,
                                                      float* __restrict__ O) {
  __shared__ __align__(16) char smem[34816];   // K dbuf 16K | V dbuf 16K; epilogue [128][68] f32
  const int t = threadIdx.x, lane = t & 63, w = t >> 6;
  const int lq = lane & 31;          // q / row index within fragment
  const int hi = lane >> 5;          // half-wave
  // block remap (round-4 verified): XCD xg owns bh {2xg, 2xg+1}; qi paired with 31-qi
  const int bidx = blockIdx.x;
  const int xg = bidx & 7, rr = bidx >> 3, hb = rr >> 5;
  const int bh = 2 * xg + hb;
  int qi = rr & 31; if (hb) qi = 31 - qi;
  const int q0 = qi * 128;
  const int b = bh >> 3, h = bh & 7;

  const int qbase = q0 + w * 32;
  const int qlane = qbase + lq;

  // Q fragments (B-operand of swapped QK^T): lane holds Q[qlane][16s+8hi+e]
  const unsigned short* Qrow = Q + (size_t)(b * Ll + qlane) * Dd + h * 64;
  bf16x8 qf[4];
#pragma unroll
  for (int s = 0; s < 4; ++s)
    qf[s] = *reinterpret_cast<const bf16x8*>(Qrow + s * 16 + hi * 8);

  f32x16 oacc[2] = {};
  float m_r = -3e38f, s_r = 0.f;

  const size_t kgbase = (size_t)(b * Ll) * Dd + h * 64;
  const size_t vgbase = (size_t)(bh * 64) * Ll;
  const int ntiles = 2 * qi + 2;
  const int ktmax = (qbase + 31) >> 6;
  const int swzl = (lq & 7) << 4;    // read-side XOR (row&7 same for lq and lq+32)

  // staging geometry: r = sr0 + 32i (0..63); sc8 = 16B chunk
  const int sr0 = t >> 3, sc8 = t & 7;

  // prologue: stage tile 0 into buffer 0
#pragma unroll
  for (int i = 0; i < 2; ++i) {
    int r = i * 32 + sr0;
    u16x8 kv = *reinterpret_cast<const u16x8*>(K + kgbase + (size_t)r * Dd + sc8 * 8);
    u16x8 vv = *reinterpret_cast<const u16x8*>(Vt + vgbase + (size_t)r * Ll + sc8 * 8);
    int dst = r * 128 + ((sc8 * 16) ^ ((r & 7) << 4));
    *reinterpret_cast<u16x8*>(smem + dst) = kv;            // K buf 0
    *reinterpret_cast<u16x8*>(smem + 16384 + dst) = vv;    // V buf 0
  }

  u16x8 kpre[2], vpre[2];
  for (int kt = 0; kt < ntiles; ++kt) {
    const int curK = (kt & 1) * 8192;          // byte offset of current K buf
    const int curV = 16384 + (kt & 1) * 8192;  // byte offset of current V buf
    __syncthreads();
    const bool pf = (kt + 1 < ntiles);
    if (pf) {
#pragma unroll
      for (int i = 0; i < 2; ++i) {
        int r = i * 32 + sr0;
        kpre[i] = *reinterpret_cast<const u16x8*>(
            K + kgbase + (size_t)((kt + 1) * 64 + r) * Dd + sc8 * 8);
        vpre[i] = *reinterpret_cast<const u16x8*>(
            Vt + vgbase + (size_t)r * Ll + (kt + 1) * 64 + sc8 * 8);
      }
    }
    if (kt <= ktmax) {
      const char* Kc = smem + curK;
      const char* Vc = smem + curV;
      // QK^T swapped: sacc[fi] = S^T for keys 32fi..32fi+31 x q-cols
      f32x16 sacc[2] = {};
      __builtin_amdgcn_s_setprio(1);
#pragma unroll
      for (int s = 0; s < 4; ++s) {
        int off = (s * 32 + hi * 16) ^ swzl;
        bf16x8 k0 = *reinterpret_cast<const bf16x8*>(Kc + lq * 128 + off);
        bf16x8 k1 = *reinterpret_cast<const bf16x8*>(Kc + (lq + 32) * 128 + off);
        sacc[0] = __builtin_amdgcn_mfma_f32_32x32x16_bf16(k0, qf[s], sacc[0], 0, 0, 0);
        sacc[1] = __builtin_amdgcn_mfma_f32_32x32x16_bf16(k1, qf[s], sacc[1], 0, 0, 0);
      }
      __builtin_amdgcn_s_setprio(0);
      // lane's S values: S[q=qlane][key = kt*64 + 32fi + (r&3)+8*(r>>2)+4*hi]
      float p[2][16];
      float pmax = -3e38f;
      if (kt * 64 + 63 > qbase) {
#pragma unroll
        for (int fi = 0; fi < 2; ++fi)
#pragma unroll
          for (int r = 0; r < 16; ++r) {
            int key = kt * 64 + 32 * fi + (r & 3) + 8 * (r >> 2) + 4 * hi;
            float v = (key > qlane) ? -3e38f : sacc[fi][r] * SCALE2;
            p[fi][r] = v;
            pmax = fmaxf(pmax, v);
          }
      } else {
#pragma unroll
        for (int fi = 0; fi < 2; ++fi)
#pragma unroll
          for (int r = 0; r < 16; ++r) {
            float v = sacc[fi][r] * SCALE2;
            p[fi][r] = v;
            pmax = fmaxf(pmax, v);
          }
      }
      pmax = fmaxf(pmax, __shfl_xor(pmax, 32));
      float mn = fmaxf(m_r, pmax);
      float alpha = exp2f(m_r - mn);
      m_r = mn;
      float rs = 0.f;
#pragma unroll
      for (int fi = 0; fi < 2; ++fi)
#pragma unroll
        for (int r = 0; r < 16; ++r) {
          float e = exp2f(p[fi][r] - mn);
          p[fi][r] = e;
          rs += e;
        }
      rs += __shfl_xor(rs, 32);
      s_r = s_r * alpha + rs;
#pragma unroll
      for (int fo = 0; fo < 2; ++fo)
#pragma unroll
        for (int r = 0; r < 16; ++r) oacc[fo][r] *= alpha;
      // pack P to bf16 pairs: wpk[fi][u] covers keys 32fi+8u+4hi+{0..3}
      unsigned wpk[2][4][2], ppk[2][4][2];
#pragma unroll
      for (int fi = 0; fi < 2; ++fi)
#pragma unroll
        for (int u = 0; u < 4; ++u) {
          wpk[fi][u][0] = (unsigned)f2b(p[fi][4 * u + 0]) | ((unsigned)f2b(p[fi][4 * u + 1]) << 16);
          wpk[fi][u][1] = (unsigned)f2b(p[fi][4 * u + 2]) | ((unsigned)f2b(p[fi][4 * u + 3]) << 16);
          ppk[fi][u][0] = __shfl_xor(wpk[fi][u][0], 32);
          ppk[fi][u][1] = __shfl_xor(wpk[fi][u][1], 32);
        }
      // PV swapped: oacc[fo] += mfma(V^T rows 32fo+lq, P-col frag)
      __builtin_amdgcn_s_setprio(1);
#pragma unroll
      for (int sp = 0; sp < 4; ++sp) {
        const int fi = sp >> 1, u0 = 2 * (sp & 1), u1 = u0 + 1;
        unsigned d0 = hi ? ppk[fi][u1][0] : wpk[fi][u0][0];
        unsigned d1 = hi ? ppk[fi][u1][1] : wpk[fi][u0][1];
        unsigned d2 = hi ? wpk[fi][u1][0] : ppk[fi][u0][0];
        unsigned d3 = hi ? wpk[fi][u1][1] : ppk[fi][u0][1];
        uint4 bdw = make_uint4(d0, d1, d2, d3);
        bf16x8 bp = *reinterpret_cast<bf16x8*>(&bdw);
        int off = (sp * 32 + hi * 16) ^ swzl;
        bf16x8 v0 = *reinterpret_cast<const bf16x8*>(Vc + lq * 128 + off);
        bf16x8 v1 = *reinterpret_cast<const bf16x8*>(Vc + (lq + 32) * 128 + off);
        oacc[0] = __builtin_amdgcn_mfma_f32_32x32x16_bf16(v0, bp, oacc[0], 0, 0, 0);
        oacc[1] = __builtin_amdgcn_mfma_f32_32x32x16_bf16(v1, bp, oacc[1], 0, 0, 0);
      }
      __builtin_amdgcn_s_setprio(0);
    }
    if (pf) {
      const int nxtK = ((kt + 1) & 1) * 8192;
      const int nxtV = 16384 + ((kt + 1) & 1) * 8192;
#pragma unroll
      for (int i = 0; i < 2; ++i) {
        int r = i * 32 + sr0;
        int dst = r * 128 + ((sc8 * 16) ^ ((r & 7) << 4));
        *reinterpret_cast<u16x8*>(smem + nxtK + dst) = kpre[i];
        *reinterpret_cast<u16x8*>(smem + nxtV + dst) = vpre[i];
      }
    }
  }
  // epilogue: oacc[fo][r] = O[q=qlane][dh=32fo+crow(r,hi)]; transpose via LDS
  __syncthreads();                       // all K/V reads done; reuse smem
  float* eb = reinterpret_cast<float*>(smem);   // [128][68] f32
  const float inv = 1.0f / s_r;
#pragma unroll
  for (int fo = 0; fo < 2; ++fo)
#pragma unroll
    for (int r = 0; r < 16; ++r) {
      int dh = 32 * fo + (r & 3) + 8 * (r >> 2) + 4 * hi;
      eb[(w * 32 + lq) * 68 + dh] = oacc[fo][r] * inv;
    }
  __syncthreads();
  const int ql = t >> 1, hf = t & 1;
  float* orow = O + (size_t)(b * Ll + q0 + ql) * Dd + h * 64 + hf * 32;
#pragma unroll
  for (int j = 0; j < 8; ++j) {
    float4 v4 = *reinterpret_cast<const float4*>(eb + ql * 68 + hf * 32 + j * 4);
    *reinterpret_cast<float4*>(orow + j * 4) = v4;
  }
}

// ---------------- launcher ----------------
extern "C" void kernel_launch(void* const* d_in, const int* in_sizes, int n_in,
                              void* d_out, int out_size, void* d_ws, size_t ws_size,
                              hipStream_t stream) {
  const float* query = (const float*)d_in[0];
  const float* key   = (const float*)d_in[1];
  const float* value = (const float*)d_in[2];
  // d_in[3] = causal mask (implied by kernel; unused)
  const float* Wq = (const float*)d_in[4];
  const float* Wk = (const float*)d_in[5];
  const float* Wv = (const float*)d_in[6];
  // d_in[7] = Wo -- present in inputs but NOT used by the reference

  unsigned short* Xbf  = (unsigned short*)d_ws;                 // 3 x M x D
  unsigned short* Wbf  = Xbf + (size_t)3 * Mm * Dd;             // 3 x D x D
  unsigned short* QKV  = Wbf + (size_t)3 * Dd * Dd;             // 3 x M x D
  unsigned short* Vt   = QKV + (size_t)3 * Mm * Dd;             // B*H*64 x L

  const int nbig = Mm * Dd / 8, nsmall = Dd * Dd / 8;
  cvt_kernel<<<nbig / 256, 256, 0, stream>>>(query, Xbf, nbig);
  cvt_kernel<<<nbig / 256, 256, 0, stream>>>(key,   Xbf + (size_t)Mm * Dd, nbig);
  cvt_kernel<<<nbig / 256, 256, 0, stream>>>(value, Xbf + (size_t)2 * Mm * Dd, nbig);
  cvt_kernel<<<nsmall / 256, 256, 0, stream>>>(Wq, Wbf, nsmall);
  cvt_kernel<<<nsmall / 256, 256, 0, stream>>>(Wk, Wbf + (size_t)Dd * Dd, nsmall);
  cvt_kernel<<<nsmall / 256, 256, 0, stream>>>(Wv, Wbf + (size_t)2 * Dd * Dd, nsmall);

  gemm_bt<<<dim3(256, 3), 256, 0, stream>>>(Xbf, Wbf, QKV);

  unsigned short* Qb = QKV;
  unsigned short* Kb = QKV + (size_t)Mm * Dd;
  unsigned short* Vb = QKV + (size_t)2 * Mm * Dd;
  transpose_v<<<dim3(64, 16), 256, 0, stream>>>(Vb, Vt);
  attn_kernel<<<512, 256, 0, stream>>>(Qb, Kb, Vt, (float*)d_out);
}